// Round 7
// baseline (168.844 us; speedup 1.0000x reference)
//
#include <hip/hip_runtime.h>

#define BSHIFT 9
#define BW 512            // nodes per bucket == bins
#define BLK 512
#define CHUNK 4096
#define CSR_CAP 18432     // LDS staging capacity (expected bucket ~16.4K edges)

// ---- block-wide exclusive scan over BLK=512 ints (wave shfl + 8-entry LDS) ----
__device__ __forceinline__ int blockScanExcl512(int v, int tid, int* wsum) {
    int lane = tid & 63;
    int w = tid >> 6;                       // 8 waves
    int incl = v;
#pragma unroll
    for (int d = 1; d < 64; d <<= 1) {
        int u = __shfl_up(incl, d, 64);
        if (lane >= d) incl += u;
    }
    if (lane == 63) wsum[w] = incl;
    __syncthreads();
    if (tid < 64) {
        int x = (tid < 8) ? wsum[tid] : 0;
#pragma unroll
        for (int d = 1; d < 8; d <<= 1) {
            int u = __shfl_up(x, d, 64);
            if (lane >= d) x += u;
        }
        if (tid < 8) wsum[tid] = x;         // inclusive scan of wave totals
    }
    __syncthreads();
    int base = (w == 0) ? 0 : wsum[w - 1];
    return base + incl - v;
}

// ---------------- pass 1: bucket histogram (int4 loads, 4 LDS replicas) ----------------
__global__ __launch_bounds__(BLK) void k_bhist(const int* __restrict__ dst,
                                               int* __restrict__ bucketCount, int E) {
    __shared__ int h[4][BW];
    int t = threadIdx.x;
#pragma unroll
    for (int r = 0; r < 4; ++r) h[r][t] = 0;
    __syncthreads();
    int* hr = h[(t >> 6) & 3];
    int gtid = blockIdx.x * BLK + t;
    int stride = gridDim.x * BLK;
    const int4* dst4 = (const int4*)dst;
    int E4 = E >> 2;
    for (int i = gtid; i < E4; i += stride) {
        int4 d = dst4[i];
        atomicAdd(&hr[d.x >> BSHIFT], 1);
        atomicAdd(&hr[d.y >> BSHIFT], 1);
        atomicAdd(&hr[d.z >> BSHIFT], 1);
        atomicAdd(&hr[d.w >> BSHIFT], 1);
    }
    for (int i = (E4 << 2) + gtid; i < E; i += stride)
        atomicAdd(&hr[dst[i] >> BSHIFT], 1);
    __syncthreads();
    int s = h[0][t] + h[1][t] + h[2][t] + h[3][t];
    if (s) atomicAdd(&bucketCount[t], s);
}

// ---------------- pass 2: bucket scan (1 block) ----------------
__global__ __launch_bounds__(BLK) void k_bscan(const int* __restrict__ bucketCount,
                                               int* __restrict__ bucketBase,
                                               int* __restrict__ bucketCursor,
                                               int NB, int E) {
    __shared__ int wsum[8];
    int t = threadIdx.x;
    int v = (t < NB) ? bucketCount[t] : 0;
    int ex = blockScanExcl512(v, t, wsum);
    if (t < NB) { bucketBase[t] = ex; bucketCursor[t] = ex; }
    if (t == NB) bucketBase[t] = E;
}

// ---------------- pass 3: chunk counting-sort by dst-bucket, coalesced flush ----------------
__global__ __launch_bounds__(BLK) void k_bin(const int* __restrict__ src,
                                             const int* __restrict__ dst,
                                             int* __restrict__ bucketCursor,
                                             unsigned int* __restrict__ binned, int E) {
    __shared__ int h0[BW], h1[BW];
    __shared__ int excl[BW], cur[BW], gbase[BW];
    __shared__ unsigned int vals[CHUNK];
    __shared__ unsigned short bkt[CHUNK];
    __shared__ int wsum[8];
    int t = threadIdx.x;
    int base = blockIdx.x * CHUNK;
    int cnt = min(CHUNK, E - base);
    h0[t] = 0; h1[t] = 0;
    __syncthreads();
    int* hr = ((t >> 6) & 1) ? h1 : h0;

    int d8[8], s8[8];
    int myBase = base + t * 8;
    int nb = 0;
    if (myBase + 8 <= E) {
        const int4* dp = (const int4*)(dst + myBase);
        const int4* sp = (const int4*)(src + myBase);
        int4 a = dp[0], b = dp[1];
        d8[0]=a.x; d8[1]=a.y; d8[2]=a.z; d8[3]=a.w;
        d8[4]=b.x; d8[5]=b.y; d8[6]=b.z; d8[7]=b.w;
        int4 c = sp[0], e = sp[1];
        s8[0]=c.x; s8[1]=c.y; s8[2]=c.z; s8[3]=c.w;
        s8[4]=e.x; s8[5]=e.y; s8[6]=e.z; s8[7]=e.w;
        nb = 8;
    } else {
        for (int k = 0; k < 8; ++k) {
            int idx = myBase + k;
            if (idx < E) { d8[k] = dst[idx]; s8[k] = src[idx]; ++nb; }
        }
    }
    for (int k = 0; k < nb; ++k) atomicAdd(&hr[d8[k] >> BSHIFT], 1);
    __syncthreads();
    int hv = h0[t] + h1[t];
    int ex = blockScanExcl512(hv, t, wsum);
    excl[t] = ex;
    cur[t] = ex;
    if (hv) gbase[t] = atomicAdd(&bucketCursor[t], hv);
    __syncthreads();
    for (int k = 0; k < nb; ++k) {
        int b = d8[k] >> BSHIFT;
        int r = atomicAdd(&cur[b], 1);
        vals[r] = ((unsigned int)s8[k] << BSHIFT) | (unsigned int)(d8[k] & (BW - 1));
        bkt[r] = (unsigned short)b;
    }
    __syncthreads();
    for (int i = t; i < cnt; i += BLK) {
        int b = bkt[i];
        binned[gbase[b] + (i - excl[b])] = vals[i];
    }
}

// ---------------- pass 4: per-bucket per-node counting sort -> CSR (+deg/dinv/xd) ----------------
__global__ __launch_bounds__(BLK) void k_csr(const unsigned int* __restrict__ binned,
                                             const int* __restrict__ bucketBase,
                                             const float* __restrict__ x,
                                             int* __restrict__ csrOff,
                                             int* __restrict__ deg,
                                             float* __restrict__ dinv,
                                             float* __restrict__ xd,
                                             int* __restrict__ csrSrc, int n) {
    __shared__ int dh0[BW], dh1[BW];
    __shared__ int cursor[BW];
    __shared__ int wsum[8];
    __shared__ int stage[CSR_CAP];         // 72 KB
    int t = threadIdx.x;
    int b = blockIdx.x;
    int ebase = bucketBase[b];
    int ecnt = bucketBase[b + 1] - ebase;
    dh0[t] = 0; dh1[t] = 0;
    __syncthreads();
    int* dh = ((t >> 6) & 1) ? dh1 : dh0;
    for (int i = t; i < ecnt; i += BLK)
        atomicAdd(&dh[binned[ebase + i] & (BW - 1)], 1);
    __syncthreads();
    int c = dh0[t] + dh1[t];
    int ex = blockScanExcl512(c, t, wsum);
    cursor[t] = ex;
    int nodeBase = b << BSHIFT;
    if (t < min(BW, n - nodeBase)) {
        int node = nodeBase + t;
        csrOff[node] = ebase + ex;
        deg[node] = c;
        float r = rsqrtf((float)(c + 1));
        dinv[node] = r;
        xd[node] = x[node] * r;
    }
    __syncthreads();
    for (int i = t; i < ecnt; i += BLK) {
        unsigned int v = binned[ebase + i];
        int r = atomicAdd(&cursor[v & (BW - 1)], 1);
        int sv = (int)(v >> BSHIFT);
        if (r < CSR_CAP) stage[r] = sv;
        else csrSrc[ebase + r] = sv;
    }
    __syncthreads();
    int m = min(ecnt, CSR_CAP);
    for (int i = t; i < m; i += BLK)
        csrSrc[ebase + i] = stage[i];
}

// ---------------- pass 5: layer-1 scalar aggregate -> sdi[n] = (s_i, dinv_i) ----------------
// 4 lanes per node, 4-deep batched loads for MLP.
__global__ __launch_bounds__(BLK) void k_l1(const int* __restrict__ csrOff,
                                            const int* __restrict__ deg,
                                            const int* __restrict__ csrSrc,
                                            const float* __restrict__ xd,
                                            const float* __restrict__ dinv,
                                            float2* __restrict__ sdi, int n) {
    int tid = threadIdx.x;
    int q = tid & 3;
    int node = blockIdx.x * (BLK / 4) + (tid >> 2);
    if (node >= n) return;
    int start = csrOff[node];
    int dc = deg[node];
    float u = 0.f;
    int e = q;
    for (; e + 12 < dc; e += 16) {
        int s0 = csrSrc[start + e];
        int s1 = csrSrc[start + e + 4];
        int s2 = csrSrc[start + e + 8];
        int s3 = csrSrc[start + e + 12];
        float x0 = xd[s0], x1 = xd[s1], x2 = xd[s2], x3 = xd[s3];
        u += (x0 + x1) + (x2 + x3);
    }
    for (; e < dc; e += 4)
        u += xd[csrSrc[start + e]];
    u += __shfl_xor(u, 1, 64);
    u += __shfl_xor(u, 2, 64);
    if (q == 0) {
        float di = dinv[node];
        sdi[node] = make_float2(di * (u + xd[node]), di);
    }
}

// ---------------- pass 6: layer-2, abs-form accumulation ----------------
// relu(z)=(z+|z|)/2:  G_j = 0.5*(W1j*Ssd + beta_j*Sd + |W1j|*M_j)
//   Ssd = sum s*di, Sd = sum di, M_j = sum di*|s - c_j|, c_j = -b1j/W1j
//   beta_j = b1j (W1j!=0) else 2*relu(b1j)
// then A[k]=sum_j W2[j][k]*G_j;  out[i] = relu(dinv_i*A + b2) . Wl + bl
__global__ __launch_bounds__(BLK) void k_l2(const int* __restrict__ csrOff,
                                            const int* __restrict__ deg,
                                            const int* __restrict__ csrSrc,
                                            const float2* __restrict__ sdi,
                                            const float* __restrict__ W1,
                                            const float* __restrict__ b1,
                                            const float* __restrict__ W2,
                                            const float* __restrict__ b2,
                                            const float* __restrict__ Wl,
                                            const float* __restrict__ bl,
                                            float* __restrict__ out, int n) {
    __shared__ float sW2[256];
    int tid = threadIdx.x;
    if (tid < 256) sW2[tid] = W2[tid];
    int q = tid & 3;
    int node = blockIdx.x * (BLK / 4) + (tid >> 2);

    // uniform constants (compiler keeps these scalar)
    float w1r[16], cr[16], betar[16];
#pragma unroll
    for (int j = 0; j < 16; ++j) {
        float w = W1[j];
        float bb = b1[j];
        w1r[j] = w;
        if (w != 0.f) { cr[j] = -bb / w; betar[j] = bb; }
        else          { cr[j] = 0.f;     betar[j] = 2.f * fmaxf(bb, 0.f); }
    }
    float4 b2q = *(const float4*)(b2 + 4 * q);
    float4 wlq = *(const float4*)(Wl + 4 * q);
    float blv = bl[0];
    __syncthreads();
    if (node >= n) return;

    int start = csrOff[node];
    int dc = deg[node];
    float M[16];
#pragma unroll
    for (int j = 0; j < 16; ++j) M[j] = 0.f;
    float Ssd = 0.f, Sd = 0.f;

    float2 aself = sdi[node];
    if (q == 0) {   // self-loop folds into the uniform accumulation
        Ssd = aself.x * aself.y;
        Sd = aself.y;
#pragma unroll
        for (int j = 0; j < 16; ++j)
            M[j] = aself.y * fabsf(aself.x - cr[j]);
    }

#define ACC(a)                                                      \
    {                                                               \
        Ssd = fmaf((a).x, (a).y, Ssd);                              \
        Sd += (a).y;                                                \
        _Pragma("unroll")                                           \
        for (int j = 0; j < 16; ++j)                                \
            M[j] = fmaf((a).y, fabsf((a).x - cr[j]), M[j]);         \
    }

    int e = q;
    for (; e + 12 < dc; e += 16) {
        int s0 = csrSrc[start + e];
        int s1 = csrSrc[start + e + 4];
        int s2 = csrSrc[start + e + 8];
        int s3 = csrSrc[start + e + 12];
        float2 a0 = sdi[s0];
        float2 a1 = sdi[s1];
        float2 a2 = sdi[s2];
        float2 a3 = sdi[s3];
        ACC(a0) ACC(a1) ACC(a2) ACC(a3)
    }
    for (; e < dc; e += 4) {
        float2 a = sdi[csrSrc[start + e]];
        ACC(a)
    }
#undef ACC

    // quad butterfly reduce: Ssd, Sd, M[16]
    Ssd += __shfl_xor(Ssd, 1, 64);
    Ssd += __shfl_xor(Ssd, 2, 64);
    Sd += __shfl_xor(Sd, 1, 64);
    Sd += __shfl_xor(Sd, 2, 64);
#pragma unroll
    for (int j = 0; j < 16; ++j) {
        M[j] += __shfl_xor(M[j], 1, 64);
        M[j] += __shfl_xor(M[j], 2, 64);
    }

    // G_j and W2 matvec: lane q owns output channels 4q..4q+3
    float4 A = make_float4(0.f, 0.f, 0.f, 0.f);
#pragma unroll
    for (int j = 0; j < 16; ++j) {
        float Gj = 0.5f * (fmaf(w1r[j], Ssd, fmaf(betar[j], Sd, fabsf(w1r[j]) * M[j])));
        float4 w = *(const float4*)(&sW2[j * 16 + 4 * q]);
        A.x = fmaf(w.x, Gj, A.x);
        A.y = fmaf(w.y, Gj, A.y);
        A.z = fmaf(w.z, Gj, A.z);
        A.w = fmaf(w.w, Gj, A.w);
    }

    float di = aself.y;
    float v0 = fmaxf(fmaf(di, A.x, b2q.x), 0.f);
    float v1 = fmaxf(fmaf(di, A.y, b2q.y), 0.f);
    float v2 = fmaxf(fmaf(di, A.z, b2q.z), 0.f);
    float v3 = fmaxf(fmaf(di, A.w, b2q.w), 0.f);
    float p = fmaf(v0, wlq.x, fmaf(v1, wlq.y, fmaf(v2, wlq.z, v3 * wlq.w)));
    p += __shfl_xor(p, 1, 64);
    p += __shfl_xor(p, 2, 64);
    if (q == 0) out[node] = p + blv;
}

extern "C" void kernel_launch(void* const* d_in, const int* in_sizes, int n_in,
                              void* d_out, int out_size, void* d_ws, size_t ws_size,
                              hipStream_t stream) {
    const float* x  = (const float*)d_in[0];
    const int*   ei = (const int*)d_in[1];
    const float* W1 = (const float*)d_in[2];
    const float* b1 = (const float*)d_in[3];
    const float* W2 = (const float*)d_in[4];
    const float* b2 = (const float*)d_in[5];
    const float* Wl = (const float*)d_in[6];
    const float* bl = (const float*)d_in[7];
    float* out = (float*)d_out;

    int n = in_sizes[0];
    int E = in_sizes[1] / 2;
    const int* srcA = ei;
    const int* dstA = ei + E;
    int NB = (n + BW - 1) >> BSHIFT;      // 391 for n=200000 (requires NB < 512)

    size_t o = 0;
    auto carve = [&](size_t bytes) {
        void* p = (char*)d_ws + o;
        o = (o + bytes + 255) & ~(size_t)255;
        return p;
    };
    int* bucketCount  = (int*)carve(BW * 4);
    int* bucketBase   = (int*)carve((BW + 1) * 4);
    int* bucketCursor = (int*)carve(BW * 4);
    int* csrOff       = (int*)carve((size_t)n * 4);
    int* deg          = (int*)carve((size_t)n * 4);
    float* dinv       = (float*)carve((size_t)n * 4);
    float* xd         = (float*)carve((size_t)n * 4);
    float2* sdi       = (float2*)carve((size_t)n * 8);
    unsigned int* binned = (unsigned int*)carve((size_t)E * 4);
    int* csrSrc       = (int*)carve((size_t)E * 4);
    (void)ws_size;

    hipMemsetAsync(bucketCount, 0, BW * 4, stream);

    k_bhist<<<512, BLK, 0, stream>>>(dstA, bucketCount, E);
    k_bscan<<<1, BLK, 0, stream>>>(bucketCount, bucketBase, bucketCursor, NB, E);
    k_bin<<<(E + CHUNK - 1) / CHUNK, BLK, 0, stream>>>(srcA, dstA, bucketCursor, binned, E);
    k_csr<<<NB, BLK, 0, stream>>>(binned, bucketBase, x, csrOff, deg, dinv, xd, csrSrc, n);

    int nodeBlocks = (n + (BLK / 4) - 1) / (BLK / 4);
    k_l1<<<nodeBlocks, BLK, 0, stream>>>(csrOff, deg, csrSrc, xd, dinv, sdi, n);
    k_l2<<<nodeBlocks, BLK, 0, stream>>>(csrOff, deg, csrSrc, sdi, W1, b1, W2, b2, Wl, bl, out, n);
}